// Round 2
// baseline (1759.625 us; speedup 1.0000x reference)
//
#include <hip/hip_runtime.h>
#include <hip/hip_bf16.h>

#define DDIM 256
#define BM 128
#define BN 128
#define BD 64
#define TM 8
#define TN 8
#define ES 140  // e_lds row stride (128 cols + 4-per-32 pad)
#define ECOL(c) ((c) + (((c) >> 5) << 2))

__global__ void enorm_kernel(const float* __restrict__ cb, float* __restrict__ en, int K) {
    int gid = blockIdx.x * blockDim.x + threadIdx.x;
    int code = gid >> 6;            // one wave per code
    int lane = threadIdx.x & 63;
    if (code >= K) return;
    const float4 v = *reinterpret_cast<const float4*>(&cb[(size_t)code * DDIM + lane * 4]);
    float s = v.x * v.x + v.y * v.y + v.z * v.z + v.w * v.w;
    #pragma unroll
    for (int off = 32; off > 0; off >>= 1) s += __shfl_xor(s, off, 64);
    if (lane == 0) en[code] = s;
}

__global__ __launch_bounds__(256, 2)
void vq_main_kernel(const float* __restrict__ x, const float* __restrict__ cb,
                    const float* __restrict__ en, float* __restrict__ out,
                    float* __restrict__ loss_accum, int N, int K) {
    __shared__ __align__(16) float xs[BD * BM];
    __shared__ __align__(16) float es[BD * ES];
    __shared__ int bidx_lds[BM];
    __shared__ float wsum[4];

    const int tid = threadIdx.x;
    const int tx = tid & 15;
    const int ty = tid >> 4;
    const int brow = blockIdx.x * BM;
    const size_t ND = (size_t)N * DDIM;

    float best[TM];
    int bidx[TM];
    #pragma unroll
    for (int m = 0; m < TM; ++m) { best[m] = 3.4e38f; bidx[m] = 0; }

    const int arow = ty * TM;            // 8-aligned row base
    const int ecol = ECOL(tx * TN);      // padded col base

    for (int kt = 0; kt < K / BN; ++kt) {
        const int c0 = kt * BN;
        float acc[TM][TN];
        #pragma unroll
        for (int m = 0; m < TM; ++m)
            #pragma unroll
            for (int n = 0; n < TN; ++n) acc[m][n] = 0.f;

        for (int dc = 0; dc < DDIM; dc += BD) {
            __syncthreads();
            // stage X chunk: xs[d][row ^ ((d>>2 & 7)<<3)]
            #pragma unroll
            for (int p = 0; p < 8; ++p) {
                int i = tid + p * 256;       // 0..2047
                int row = i >> 4;            // 0..127
                int dq = i & 15;             // 0..15 (d-quad)
                const float4 v = *reinterpret_cast<const float4*>(
                    &x[(size_t)(brow + row) * DDIM + dc + dq * 4]);
                int col = row ^ ((dq & 7) << 3);
                int b = dq * 4 * BM + col;
                xs[b] = v.x; xs[b + BM] = v.y; xs[b + 2 * BM] = v.z; xs[b + 3 * BM] = v.w;
            }
            // stage E chunk: es[d][ECOL(code)]
            #pragma unroll
            for (int p = 0; p < 8; ++p) {
                int i = tid + p * 256;
                int code = i >> 4;
                int dq = i & 15;
                const float4 v = *reinterpret_cast<const float4*>(
                    &cb[(size_t)(c0 + code) * DDIM + dc + dq * 4]);
                int b = dq * 4 * ES + ECOL(code);
                es[b] = v.x; es[b + ES] = v.y; es[b + 2 * ES] = v.z; es[b + 3 * ES] = v.w;
            }
            __syncthreads();

            #pragma unroll 4
            for (int d = 0; d < BD; ++d) {
                int sw = ((d >> 2) & 7) << 3;
                const float4 a0 = *reinterpret_cast<const float4*>(&xs[d * BM + (arow ^ sw)]);
                const float4 a1 = *reinterpret_cast<const float4*>(&xs[d * BM + (arow ^ sw) + 4]);
                const float4 b0 = *reinterpret_cast<const float4*>(&es[d * ES + ecol]);
                const float4 b1 = *reinterpret_cast<const float4*>(&es[d * ES + ecol + 4]);
                float a[TM] = {a0.x, a0.y, a0.z, a0.w, a1.x, a1.y, a1.z, a1.w};
                float b[TN] = {b0.x, b0.y, b0.z, b0.w, b1.x, b1.y, b1.z, b1.w};
                #pragma unroll
                for (int m = 0; m < TM; ++m)
                    #pragma unroll
                    for (int n = 0; n < TN; ++n)
                        acc[m][n] = fmaf(a[m], b[n], acc[m][n]);
            }
        }

        // fused argmin epilogue: dist = ||e||^2 - 2*dot (x-norm constant per row)
        #pragma unroll
        for (int n = 0; n < TN; ++n) {
            int code = c0 + tx * TN + n;
            float e = en[code];
            #pragma unroll
            for (int m = 0; m < TM; ++m) {
                float dist = fmaf(-2.f, acc[m][n], e);
                if (dist < best[m]) { best[m] = dist; bidx[m] = code; }
            }
        }
    }

    // cross-lane argmin: 16 lanes (same ty) own disjoint code subsets for same rows
    #pragma unroll
    for (int m = 0; m < TM; ++m) {
        float d = best[m];
        int ix = bidx[m];
        #pragma unroll
        for (int off = 1; off < 16; off <<= 1) {
            float od = __shfl_xor(d, off, 64);
            int oi = __shfl_xor(ix, off, 64);
            if (od < d || (od == d && oi < ix)) { d = od; ix = oi; }
        }
        if (tx == 0) bidx_lds[arow + m] = ix;
    }
    __syncthreads();

    // indices out, as float32 values (fp32 exact for idx < 2^24)
    if (tid < BM) {
        out[ND + 1 + brow + tid] = (float)bidx_lds[tid];
    }

    // gather quantized rows, write fp32, accumulate commitment loss
    float lsum = 0.f;
    #pragma unroll 4
    for (int p = 0; p < 32; ++p) {
        int i = tid + p * 256;       // 0..8191 float4-units
        int row = i >> 6;            // 0..127
        int c4 = (i & 63) << 2;      // 0..252
        int code = bidx_lds[row];
        const float4 q = *reinterpret_cast<const float4*>(&cb[(size_t)code * DDIM + c4]);
        const float4 xv = *reinterpret_cast<const float4*>(&x[(size_t)(brow + row) * DDIM + c4]);
        float d0 = xv.x - q.x, d1 = xv.y - q.y, d2 = xv.z - q.z, d3 = xv.w - q.w;
        lsum += d0 * d0 + d1 * d1 + d2 * d2 + d3 * d3;
        *reinterpret_cast<float4*>(&out[(size_t)(brow + row) * DDIM + c4]) = q;
    }
    #pragma unroll
    for (int off = 32; off > 0; off >>= 1) lsum += __shfl_xor(lsum, off, 64);
    if ((tid & 63) == 0) wsum[tid >> 6] = lsum;
    __syncthreads();
    if (tid == 0) {
        float tot = wsum[0] + wsum[1] + wsum[2] + wsum[3];
        atomicAdd(loss_accum, tot * (0.25f / (float)ND));
    }
}

__global__ void loss_fin_kernel(const float* __restrict__ loss_accum,
                                float* __restrict__ out, size_t off) {
    if (blockIdx.x == 0 && threadIdx.x == 0) out[off] = *loss_accum;
}

extern "C" void kernel_launch(void* const* d_in, const int* in_sizes, int n_in,
                              void* d_out, int out_size, void* d_ws, size_t ws_size,
                              hipStream_t stream) {
    const float* x = (const float*)d_in[0];
    const float* cb = (const float*)d_in[1];
    const int D = DDIM;
    const int N = in_sizes[0] / D;   // 65536
    const int K = in_sizes[1] / D;   // 4096
    float* out = (float*)d_out;

    float* enorm = (float*)d_ws;
    float* loss_accum = enorm + K;

    hipMemsetAsync(loss_accum, 0, sizeof(float), stream);
    enorm_kernel<<<(K * 64 + 255) / 256, 256, 0, stream>>>(cb, enorm, K);
    vq_main_kernel<<<N / BM, 256, 0, stream>>>(x, cb, enorm, out, loss_accum, N, K);
    loss_fin_kernel<<<1, 64, 0, stream>>>(loss_accum, out, (size_t)N * D);
}